// Round 11
// baseline (549.928 us; speedup 1.0000x reference)
//
#include <hip/hip_runtime.h>
#include <stdint.h>

typedef float f32x4 __attribute__((ext_vector_type(4)));
typedef short s16x8 __attribute__((ext_vector_type(8)));
typedef unsigned u32x4 __attribute__((ext_vector_type(4)));

#define B_SZ 256
#define A_RG 196
#define DVD  2048
#define RNN  1024
#define H_SZ 512
#define M_TOT (B_SZ * A_RG)   // 50176 flat rows
#define NKT  (DVD / 32)       // 64 K-tiles
#define NMT  (M_TOT / 64)     // 784 wave-tiles (64 rows each)

__device__ __forceinline__ unsigned short f2bf(float f) {
    unsigned u = __builtin_bit_cast(unsigned, f);
    u = u + 0x7FFFu + ((u >> 16) & 1u);   // RNE
    return (unsigned short)(u >> 16);
}

__device__ __forceinline__ unsigned cvt2(float a, float b) {
    unsigned r;
    asm("v_cvt_pk_bf16_f32 %0, %1, %2" : "=v"(r) : "v"(a), "v"(b));
    return r;
}

// ---------------------------------------------------------------------------
// Kernel 1: W_v [2048,512] fp32 -> Wt4 bf16 packed in MFMA-B-fragment order
// (R9-verified layout): ushort idx = ((kt*32 + f)*64 + g*16 + lr)*8 + e
// where f=col>>4, lr=col&15, kt=k>>5, g=(k>>3)&3, e=k&7. One wave B-frag
// load = contiguous 1KB global_load_dwordx4.
// ---------------------------------------------------------------------------
__global__ __launch_bounds__(256) void k_prepW(const float* __restrict__ Wv,
                                               unsigned short* __restrict__ Wt4) {
    __shared__ float tile[64][65];
    int kb = blockIdx.x >> 3, ct = blockIdx.x & 7;
    int k0 = kb * 64, c0 = ct * 64;
    int t = threadIdx.x;
    int cl = t & 63, rq = t >> 6;
#pragma unroll
    for (int i = 0; i < 16; ++i) {
        int r = rq * 16 + i;
        tile[r][cl] = Wv[(size_t)(k0 + r) * H_SZ + c0 + cl];
    }
    __syncthreads();
    int kl = t & 63;
#pragma unroll
    for (int i = 0; i < 16; ++i) {
        int cr = rq * 16 + i;
        int col = c0 + cr;
        int k = k0 + kl;
        int f = col >> 4, lr = col & 15;
        int kt = k >> 5, g = (k >> 3) & 3, e = k & 7;
        size_t dst = ((size_t)(kt * 32 + f) * 64 + g * 16 + lr) * 8 + e;
        Wt4[dst] = f2bf(tile[kl][cr]);
    }
}

// ---------------------------------------------------------------------------
// Kernel 2: base[b,h] = h_att[b]@W_ha + prev_h2[b]@W_hv + b_ha + b_hv + b_v
// ---------------------------------------------------------------------------
__global__ __launch_bounds__(256) void k_base(const float* __restrict__ h_att,
                                              const float* __restrict__ prev_h2,
                                              const float* __restrict__ W_ha,
                                              const float* __restrict__ b_ha,
                                              const float* __restrict__ W_hv,
                                              const float* __restrict__ b_hv,
                                              const float* __restrict__ b_v,
                                              float* __restrict__ base_g) {
    __shared__ float ha_s[4][RNN];
    __shared__ float pv_s[4][RNN];
    int bg = blockIdx.x >> 2, hg = blockIdx.x & 3;
    int t = threadIdx.x;
#pragma unroll
    for (int i = 0; i < 16; ++i) {
        int idx = i * 256 + t;
        int bl = idx >> 10, k = idx & 1023;
        ha_s[bl][k] = h_att[(size_t)(bg * 4 + bl) * RNN + k];
        pv_s[bl][k] = prev_h2[(size_t)(bg * 4 + bl) * RNN + k];
    }
    __syncthreads();
    int h = hg * 128 + (t & 127);
    int br = t >> 7;
    float aA0 = 0, aA1 = 0, aV0 = 0, aV1 = 0;
#pragma unroll 4
    for (int k = 0; k < RNN; ++k) {
        float w1 = W_ha[(size_t)k * H_SZ + h];
        float w2 = W_hv[(size_t)k * H_SZ + h];
        aA0 = fmaf(ha_s[br * 2][k],     w1, aA0);
        aA1 = fmaf(ha_s[br * 2 + 1][k], w1, aA1);
        aV0 = fmaf(pv_s[br * 2][k],     w2, aV0);
        aV1 = fmaf(pv_s[br * 2 + 1][k], w2, aV1);
    }
    float bias = b_ha[h] + b_hv[h] + b_v[h];
    base_g[(size_t)(bg * 4 + br * 2) * H_SZ + h]     = aA0 + aV0 + bias;
    base_g[(size_t)(bg * 4 + br * 2 + 1) * H_SZ + h] = aA1 + aV1 + bias;
}

// ---------------------------------------------------------------------------
// Kernel 3: barrier-free, LDS-free GEMM. One independent WAVE per 64x128
// output tile: A fragments loaded straight from global into regs (lane reads
// its own 32B at row*8KB -> 16 full 128B lines per instr) and cvt_pk'd to
// bf16; B fragments register-direct from the L2-resident fragment-packed
// Wt4 (8 x 1KB contiguous per tile). No syncthreads anywhere; per-wave
// latency hidden by 8 independent waves/CU. acc[4][8]=128 + ~90 others
// -> ~220 unified regs, 2 waves/SIMD. Epilogue: partial score over the
// wave's 128 cols -> att4[nc][row] (combined in k_ws).
// Block = 4 waves = 4 CONSECUTIVE mtiles, same nc (no duplicate A reads).
// ---------------------------------------------------------------------------
__global__ __launch_bounds__(256, 2) void k_gemm(const float* __restrict__ imgs,
                                                 const unsigned short* __restrict__ Wt4,
                                                 const float* __restrict__ base_g,
                                                 const float* __restrict__ W_f,
                                                 float* __restrict__ att4) {
    const int t = threadIdx.x;
    const int lane = t & 63, w = t >> 6;
    const int nc    = blockIdx.x / 196;              // 0..3 (h-chunk)
    const int mtile = (blockIdx.x % 196) * 4 + w;    // 0..783
    const int m0 = mtile * 64;
    const int lr = lane & 15, g = lane >> 4;

    // ---- A fragment sources: mfrag mf -> lane reads 32B at
    //      (m0 + mf*16 + lr)*8KB + g*32 + kt*128 ----
    const char* Ap0 = (const char*)imgs + (size_t)(m0 + 0 * 16 + lr) * (DVD * 4) + g * 32;
    const char* Ap1 = (const char*)imgs + (size_t)(m0 + 1 * 16 + lr) * (DVD * 4) + g * 32;
    const char* Ap2 = (const char*)imgs + (size_t)(m0 + 2 * 16 + lr) * (DVD * 4) + g * 32;
    const char* Ap3 = (const char*)imgs + (size_t)(m0 + 3 * 16 + lr) * (DVD * 4) + g * 32;

    // ---- B fragment source: frag f = nc*8+n of tile kt at
    //      byte ((kt*32 + nc*8 + n)*64 + lane)*16 ----
    const char* Bp = (const char*)Wt4 + ((size_t)(nc * 8) * 64 + lane) * 16;

    f32x4 acc[4][8] = {};
    f32x4 rA[4][2];
    s16x8 aF[4], bR[8];

    auto issueA = [&](int kt) {
        const size_t o = (size_t)kt * 128;
        rA[0][0] = *(const f32x4*)(Ap0 + o);  rA[0][1] = *(const f32x4*)(Ap0 + o + 16);
        rA[1][0] = *(const f32x4*)(Ap1 + o);  rA[1][1] = *(const f32x4*)(Ap1 + o + 16);
        rA[2][0] = *(const f32x4*)(Ap2 + o);  rA[2][1] = *(const f32x4*)(Ap2 + o + 16);
        rA[3][0] = *(const f32x4*)(Ap3 + o);  rA[3][1] = *(const f32x4*)(Ap3 + o + 16);
    };
    auto issueB = [&](int kt) {
        const char* p = Bp + (size_t)kt * 32768;
#pragma unroll
        for (int n = 0; n < 8; ++n)
            bR[n] = *(const s16x8*)(p + n * 1024);
    };
    auto cvtA = [&]() {
#pragma unroll
        for (int mf = 0; mf < 4; ++mf) {
            u32x4 pk;
            pk[0] = cvt2(rA[mf][0][0], rA[mf][0][1]);
            pk[1] = cvt2(rA[mf][0][2], rA[mf][0][3]);
            pk[2] = cvt2(rA[mf][1][0], rA[mf][1][1]);
            pk[3] = cvt2(rA[mf][1][2], rA[mf][1][3]);
            aF[mf] = __builtin_bit_cast(s16x8, pk);
        }
    };

    // ---- prologue ----
    issueA(0);
    issueB(0);
    cvtA();                     // waits A(0); B(0) still in flight

    // ---- barrier-free K loop ----
    for (int kt = 0; kt < NKT; ++kt) {
        if (kt + 1 < NKT) issueA(kt + 1);   // in flight across the MFMAs
        __builtin_amdgcn_s_setprio(1);
#pragma unroll
        for (int mf = 0; mf < 4; ++mf)
#pragma unroll
            for (int n = 0; n < 8; ++n)
                acc[mf][n] = __builtin_amdgcn_mfma_f32_16x16x32_bf16(
                    aF[mf], bR[n], acc[mf][n], 0, 0, 0);
        __builtin_amdgcn_s_setprio(0);
        if (kt + 1 < NKT) {
            issueB(kt + 1);     // WAR after last bR use; counted vmcnt on next use
            cvtA();             // waits A(kt+1) only
        }
    }

    // ---- epilogue: partial score over this wave's 128 cols ----
    const int b0 = m0 / A_RG;
    const int b1 = min(b0 + 1, B_SZ - 1);
    float wfv[8], bs0[8], bs1[8];
#pragma unroll
    for (int n = 0; n < 8; ++n) {
        int col = nc * 128 + n * 16 + lr;
        wfv[n] = W_f[col];
        bs0[n] = base_g[(size_t)b0 * H_SZ + col];
        bs1[n] = base_g[(size_t)b1 * H_SZ + col];
    }
    float* dst = att4 + (size_t)nc * M_TOT + m0;
#pragma unroll
    for (int mf = 0; mf < 4; ++mf) {
        float pj[4] = {0.f, 0.f, 0.f, 0.f};
#pragma unroll
        for (int j = 0; j < 4; ++j) {
            int row = mf * 16 + g * 4 + j;
            bool second = (m0 + row) >= (b0 + 1) * A_RG;
#pragma unroll
            for (int n = 0; n < 8; ++n) {
                float bsv = second ? bs1[n] : bs0[n];
                pj[j] += fmaxf(acc[mf][n][j] + bsv, 0.f) * wfv[n];
            }
        }
#pragma unroll
        for (int j = 0; j < 4; ++j) {
            float s = pj[j];
            s += __shfl_xor(s, 1);
            s += __shfl_xor(s, 2);
            s += __shfl_xor(s, 4);
            s += __shfl_xor(s, 8);     // sum over the 16 lr-lanes of this row
            if (lr == 0)
                dst[mf * 16 + g * 4 + j] = s;   // unique writer per (nc,row)
        }
    }
}

// ---------------------------------------------------------------------------
// Kernel 4: combine 4 nc-partials -> softmax over A=196 -> weighted sum.
// grid (2 d-halves, 256 b), block 256; thread t owns one f32x4 col group.
// ---------------------------------------------------------------------------
__global__ __launch_bounds__(256) void k_ws(const float* __restrict__ imgs,
                                            const float* __restrict__ att4,
                                            float* __restrict__ out) {
    __shared__ float alpha_s[A_RG];
    int b = blockIdx.y, dc = blockIdx.x;
    int t = threadIdx.x;

    if (t < 64) {
        float v[4], e[4];
        float mx = -1e30f;
#pragma unroll
        for (int i = 0; i < 4; ++i) {
            int r = i * 64 + t;
            if (r < A_RG) {
                size_t idx = (size_t)b * A_RG + r;
                v[i] = (att4[idx] + att4[(size_t)M_TOT + idx])
                     + (att4[2 * (size_t)M_TOT + idx] + att4[3 * (size_t)M_TOT + idx]);
            } else v[i] = -1e30f;
            mx = fmaxf(mx, v[i]);
        }
        for (int d = 1; d < 64; d <<= 1) mx = fmaxf(mx, __shfl_xor(mx, d));
        float sum = 0.f;
#pragma unroll
        for (int i = 0; i < 4; ++i) {
            int r = i * 64 + t;
            e[i] = (r < A_RG) ? __expf(v[i] - mx) : 0.f;
            sum += e[i];
        }
        for (int d = 1; d < 64; d <<= 1) sum += __shfl_xor(sum, d);
        float inv = 1.0f / sum;
#pragma unroll
        for (int i = 0; i < 4; ++i) {
            int r = i * 64 + t;
            if (r < A_RG) alpha_s[r] = e[i] * inv;
        }
    }
    __syncthreads();

    const float* ib = imgs + (size_t)b * A_RG * DVD + dc * 1024 + t * 4;
    f32x4 o0 = {}, o1 = {}, o2 = {}, o3 = {};
    for (int a = 0; a < A_RG; a += 4) {           // 196 = 49*4 exact
        float al0 = alpha_s[a],     al1 = alpha_s[a + 1];
        float al2 = alpha_s[a + 2], al3 = alpha_s[a + 3];
        f32x4 v0 = *(const f32x4*)(ib + (size_t)(a)     * DVD);
        f32x4 v1 = *(const f32x4*)(ib + (size_t)(a + 1) * DVD);
        f32x4 v2 = *(const f32x4*)(ib + (size_t)(a + 2) * DVD);
        f32x4 v3 = *(const f32x4*)(ib + (size_t)(a + 3) * DVD);
#pragma unroll
        for (int j = 0; j < 4; ++j) {
            o0[j] = fmaf(al0, v0[j], o0[j]);
            o1[j] = fmaf(al1, v1[j], o1[j]);
            o2[j] = fmaf(al2, v2[j], o2[j]);
            o3[j] = fmaf(al3, v3[j], o3[j]);
        }
    }
    f32x4 o;
#pragma unroll
    for (int j = 0; j < 4; ++j) o[j] = (o0[j] + o1[j]) + (o2[j] + o3[j]);
    *(f32x4*)(out + (size_t)b * DVD + dc * 1024 + t * 4) = o;
}

// ---------------------------------------------------------------------------
extern "C" void kernel_launch(void* const* d_in, const int* in_sizes, int n_in,
                              void* d_out, int out_size, void* d_ws, size_t ws_size,
                              hipStream_t stream) {
    const float* h_att   = (const float*)d_in[0];
    const float* prev_h2 = (const float*)d_in[1];
    const float* imgs    = (const float*)d_in[2];
    const float* W_v     = (const float*)d_in[3];
    const float* b_v     = (const float*)d_in[4];
    const float* W_ha    = (const float*)d_in[5];
    const float* b_ha    = (const float*)d_in[6];
    const float* W_hv    = (const float*)d_in[7];
    const float* b_hv    = (const float*)d_in[8];
    const float* W_f     = (const float*)d_in[9];
    // d_in[10] = b_f: softmax-invariant additive constant -> unused

    // ws layout: [0,2MB) Wt4 bf16 fragment-packed; [2MB,+512KB) base fp32
    // [256][512]; then att4 fp32 [4][50176]
    unsigned short* Wt4 = (unsigned short*)d_ws;
    float* base_g = (float*)((char*)d_ws + (size_t)DVD * H_SZ * 2);
    float* att4   = (float*)((char*)d_ws + (size_t)DVD * H_SZ * 2 + (size_t)B_SZ * H_SZ * 4);
    float* out = (float*)d_out;

    hipLaunchKernelGGL(k_prepW, dim3(256), dim3(256), 0, stream, W_v, Wt4);
    hipLaunchKernelGGL(k_base, dim3(256), dim3(256), 0, stream,
                       h_att, prev_h2, W_ha, b_ha, W_hv, b_hv, b_v, base_g);
    hipLaunchKernelGGL(k_gemm, dim3(784), dim3(256), 0, stream,
                       imgs, Wt4, base_g, W_f, att4);
    hipLaunchKernelGGL(k_ws, dim3(2, B_SZ), dim3(256), 0, stream,
                       imgs, att4, out);
}